// Round 29
// baseline (113.684 us; speedup 1.0000x reference)
//
#include <hip/hip_runtime.h>
#include <math.h>

#define IN_CH 256
#define OUT_CH 64
#define SCHUNK 512  // scan elements per block (needs n <= 256*SCHUNK = 131072)

typedef unsigned short ushort;
typedef unsigned int uint32x4 __attribute__((ext_vector_type(4)));
typedef __bf16 bf16x8 __attribute__((ext_vector_type(8)));
typedef float f32x4 __attribute__((ext_vector_type(4)));

__device__ __forceinline__ ushort bf16rne(float v) {
  unsigned u = __float_as_uint(v);
  return (ushort)((u + 0x7FFFu + ((u >> 16) & 1u)) >> 16);
}
__device__ __forceinline__ float bf16dec(ushort h) {
  return __uint_as_float((unsigned)h << 16);
}
__device__ __forceinline__ unsigned rne16(unsigned u) {   // fp32 bits -> bf16 bits (RNE)
  return (u + 0x7FFFu + ((u >> 16) & 1u)) >> 16;
}

// async global->LDS DMA, 16B per lane: lds dest = base + lane*16 (wave-uniform base),
// global src is PER-LANE. Queued on vmcnt; __syncthreads() drains it.
__device__ __forceinline__ void gload_lds16(const void* g, void* l) {
  __builtin_amdgcn_global_load_lds(
      (const __attribute__((address_space(1))) unsigned int*)g,
      (__attribute__((address_space(3))) unsigned int*)l,
      16, 0, 0);
}

// ---------- K0: fused prep — cnt/e clear + int64 detect + W -> bf16 (RNE, no split) ----------
__global__ __launch_bounds__(256) void gat_prep(
    const float* __restrict__ W, ushort* __restrict__ Whi,
    const unsigned* __restrict__ eidx, unsigned* __restrict__ flag,
    int* __restrict__ cnt, float* __restrict__ e, int n, int npairs)
{
  __shared__ unsigned wsh[4];
  const int b = blockIdx.x, tid = threadIdx.x;
  const int i = b * 256 + tid;
  if (i < n) { cnt[i] = 0; e[i] = 0.f; }
  if (b == 0) {
    unsigned v = 0;
    for (int k = tid; k < npairs; k += 256) v |= eidx[2 * k + 1];
#pragma unroll
    for (int m = 1; m < 64; m <<= 1) v |= __shfl_xor(v, m);
    if ((tid & 63) == 0) wsh[tid >> 6] = v;
    __syncthreads();
    if (tid == 0) *flag = wsh[0] | wsh[1] | wsh[2] | wsh[3];
  } else if (b <= 64) {
    int j = (b - 1) * 256 + tid;                   // 0..16383
    int ee = j & 7, ln = (j >> 3) & 63, ctks = j >> 9;
    int ct = ctks & 3, ks = ctks >> 2;
    int k = ks * 32 + (ln >> 4) * 8 + ee;
    int col = ct * 16 + (ln & 15);
    Whi[j] = bf16rne(W[(size_t)k * OUT_CH + col]);
  }
}

// ---------- K1: fused phase2 — gemm blocks (0..gb-1) CO-RESIDENT with pass1 blocks ----------
// gemm path: DMA-dbuf SINGLE-bf16 MFMA (Wh is stored bf16 anyway; split precision
// was wasted). 1 MFMA + 1 W-load per ks. pass1: 2-way unrolled edge decode+count.
// Split 320 gemm / 448 pass1 (balanced for the lighter gemm).
template <typename IDX>
__global__ __launch_bounds__(256, 3) void gat_phase2(
    const float* __restrict__ x, const ushort* __restrict__ Whi,
    const float* __restrict__ a_src, const float* __restrict__ a_dst,
    ushort* __restrict__ Wh, float* __restrict__ e, int n, int ntiles, int gemm_blocks,
    const void* __restrict__ eidx, const unsigned* __restrict__ flag,
    int* __restrict__ cnt, void* __restrict__ rcbuf, IDX* __restrict__ rank, int E)
{
  __shared__ __align__(16) float Ax[2][16 * 256];  // 2 x 16KB x-frag buffers (gemm path)
  const int tid = threadIdx.x;

  if ((int)blockIdx.x >= gemm_blocks) {
    // ---- pass1 path: persistent, grid-stride, 2 independent chains in flight ----
    const int pb = blockIdx.x - gemm_blocks;
    const int nthr = (gridDim.x - gemm_blocks) * 256;
    const bool is64 = (*flag == 0);
    const long long* p64 = (const long long*)eidx;
    const int* p32 = (const int*)eidx;
    int j = pb * 256 + tid;
    for (; j + nthr < E; j += 2 * nthr) {
      int jA = j, jB = j + nthr;
      int rA, cA, rB, cB;
      if (is64) {
        rA = (int)p64[jA]; cA = (int)p64[(size_t)E + jA];
        rB = (int)p64[jB]; cB = (int)p64[(size_t)E + jB];
      } else {
        rA = p32[jA]; cA = p32[(size_t)E + jA];
        rB = p32[jB]; cB = p32[(size_t)E + jB];
      }
      int kA = atomicAdd(cnt + cA, 1);
      int kB = atomicAdd(cnt + cB, 1);
      if constexpr (sizeof(IDX) == 2) {
        ((unsigned*)rcbuf)[jA] = ((unsigned)cA << 16) | (unsigned)rA;
        ((unsigned*)rcbuf)[jB] = ((unsigned)cB << 16) | (unsigned)rB;
      } else {
        ((uint2*)rcbuf)[jA] = make_uint2((unsigned)rA, (unsigned)cA);
        ((uint2*)rcbuf)[jB] = make_uint2((unsigned)rB, (unsigned)cB);
      }
      rank[jA] = (IDX)kA;
      rank[jB] = (IDX)kB;
    }
    for (; j < E; j += nthr) {
      int r, c;
      if (is64) { r = (int)p64[j]; c = (int)p64[(size_t)E + j]; }
      else      { r = p32[j];      c = p32[(size_t)E + j]; }
      int rk = atomicAdd(cnt + c, 1);
      if constexpr (sizeof(IDX) == 2) {
        ((unsigned*)rcbuf)[j] = ((unsigned)c << 16) | (unsigned)r;
      } else {
        ((uint2*)rcbuf)[j] = make_uint2((unsigned)r, (unsigned)c);
      }
      rank[j] = (IDX)rk;
    }
    return;
  }

  // ---- gemm path ----
  const int lane = tid & 63;
  const int ct = tid >> 6;             // wave id = column tile
  const int lg = lane >> 4;            // k-pack group
  const int li = lane & 15;            // row (A) / col (B/D)
  const int stride = gemm_blocks;

  const int col = ct * 16 + li;
  const float asd = a_src[col] + a_dst[col];

  // issue tile t's 16 DMA chunks into Ax[buf]; wave ct owns chunks ct*4..ct*4+3
  auto issue = [&](int t, int buf) {
    int arow = t * 16 + li; if (arow > n - 1) arow = n - 1;
    const float* __restrict__ xr = x + (size_t)arow * IN_CH;
#pragma unroll
    for (int cc = 0; cc < 4; ++cc) {
      const int chunk = ct * 4 + cc;               // = ks*2 + h
      const int ks = chunk >> 1, h = chunk & 1;
      gload_lds16(xr + ks * 32 + lg * 8 + h * 4, &Ax[buf][chunk * 256]);
    }
  };

  int t = blockIdx.x;
  if (t < ntiles) issue(t, 0);
  __syncthreads();                                 // buf0 DMA drained
  int buf = 0;

  while (t < ntiles) {
    const int tn = t + stride;
    if (tn < ntiles) issue(tn, buf ^ 1);           // async prefetch, can't be sunk

    const int row0 = t * 16;
    f32x4 acc = {0.f, 0.f, 0.f, 0.f};
#pragma unroll
    for (int ks = 0; ks < 8; ++ks) {
      float4 v0 = *(const float4*)&Ax[buf][(ks * 2 + 0) * 256 + lane * 4];
      float4 v1 = *(const float4*)&Ax[buf][(ks * 2 + 1) * 256 + lane * 4];
      unsigned b0 = __float_as_uint(v0.x), b1 = __float_as_uint(v0.y);
      unsigned b2 = __float_as_uint(v0.z), b3 = __float_as_uint(v0.w);
      unsigned b4 = __float_as_uint(v1.x), b5 = __float_as_uint(v1.y);
      unsigned b6 = __float_as_uint(v1.z), b7 = __float_as_uint(v1.w);
      uint32x4 hv = { (rne16(b1) << 16) | rne16(b0),
                      (rne16(b3) << 16) | rne16(b2),
                      (rne16(b5) << 16) | rne16(b4),
                      (rne16(b7) << 16) | rne16(b6) };
      bf16x8 ah = __builtin_bit_cast(bf16x8, hv);
      bf16x8 wh = __builtin_bit_cast(bf16x8, ((const uint4*)Whi)[(ks * 4 + ct) * 64 + lane]);
      acc = __builtin_amdgcn_mfma_f32_16x16x32_bf16(ah, wh, acc, 0, 0, 0);
    }

    // epilogue: Wh bf16 store + e partial via atomicAdd
#pragma unroll
    for (int r = 0; r < 4; ++r) {
      int row = row0 + lg * 4 + r;
      bool ok = row < n;
      if (ok) Wh[(size_t)row * OUT_CH + col] = bf16rne(acc[r]);
      float pe = acc[r] * asd;
      pe += __shfl_xor(pe, 1); pe += __shfl_xor(pe, 2);
      pe += __shfl_xor(pe, 4); pe += __shfl_xor(pe, 8);
      if (ok && li == 0) atomicAdd(e + row, pe);   // 4 ct-partials per row
    }

    __syncthreads();     // drains t+1's DMAs; buf safe to overwrite next iter
    buf ^= 1;
    t = tn;
  }
}

// ---------- K4a/b: hierarchical exclusive scan of cnt -> segp; q = exp(e) fused ----------
__global__ __launch_bounds__(256) void scan_partial(
    const int* __restrict__ cnt, int* __restrict__ bsum, int n)
{
  int base = blockIdx.x * SCHUNK;
  int tid = threadIdx.x;
  int s = 0;
  int i0 = base + tid, i1 = base + tid + 256;
  if (i0 < n) s += cnt[i0];
  if (i1 < n) s += cnt[i1];
#pragma unroll
  for (int m = 1; m < 64; m <<= 1) s += __shfl_xor(s, m);
  __shared__ int ws[4];
  if ((tid & 63) == 0) ws[tid >> 6] = s;
  __syncthreads();
  if (tid == 0) bsum[blockIdx.x] = ws[0] + ws[1] + ws[2] + ws[3];
}

__global__ __launch_bounds__(256) void scan_final(
    const int* __restrict__ cnt, const int* __restrict__ bsum,
    int* __restrict__ segp, const float* __restrict__ e, float* __restrict__ q,
    int n, int nb, int E)
{
  __shared__ int sh[256];
  __shared__ int bexcl_sh;
  int tid = threadIdx.x;
  int bv = (tid < nb) ? bsum[tid] : 0;
  sh[tid] = bv;
  __syncthreads();
  for (int off = 1; off < 256; off <<= 1) {
    int add = (tid >= off) ? sh[tid - off] : 0;
    __syncthreads();
    sh[tid] += add;
    __syncthreads();
  }
  if (tid == 0) bexcl_sh = sh[blockIdx.x] - bsum[blockIdx.x];
  __syncthreads();
  int bexcl = bexcl_sh;
  __syncthreads();   // done reading sh as bsum-scan; reuse below

  int base = blockIdx.x * SCHUNK;
  int i0 = base + 2 * tid, i1 = i0 + 1;
  int c0 = (i0 < n) ? cnt[i0] : 0;
  int c1 = (i1 < n) ? cnt[i1] : 0;
  int ps = c0 + c1;
  sh[tid] = ps;
  __syncthreads();
  for (int off = 1; off < 256; off <<= 1) {
    int add = (tid >= off) ? sh[tid - off] : 0;
    __syncthreads();
    sh[tid] += add;
    __syncthreads();
  }
  int excl = sh[tid] - ps + bexcl;
  if (i0 < n) { segp[i0] = excl;      q[i0] = __expf(fminf(e[i0], 80.f)); }
  if (i1 < n) { segp[i1] = excl + c0; q[i1] = __expf(fminf(e[i1], 80.f)); }
  if (blockIdx.x == 0 && tid == 0) segp[n] = E;
}

// ---------- K5: atomic-free CSR scatter: perm[segp[c]+rank] = r ----------
template <typename IDX>
__global__ void gat_scatter(
    const void* __restrict__ rcbuf, const IDX* __restrict__ rank,
    const int* __restrict__ segp, IDX* __restrict__ perm, int E)
{
  int j = blockIdx.x * blockDim.x + threadIdx.x;
  if (j >= E) return;
  unsigned r, c;
  if constexpr (sizeof(IDX) == 2) {
    unsigned p = ((const unsigned*)rcbuf)[j];
    r = p & 0xFFFFu; c = p >> 16;
  } else {
    uint2 p = ((const uint2*)rcbuf)[j];
    r = p.x; c = p.y;
  }
  perm[segp[c] + (int)rank[j]] = (IDX)r;
}

// ---------- K6: aggregate + ELU; factorized softmax, scalarized gathers ----------
// out_c = sum_r q[r]*Wh[r] / sum_r q[r]  — the q[c] factor cancels analytically.
template <typename IDX>
__global__ __launch_bounds__(256) void gat_aggregate(
    const ushort* __restrict__ Wh, const float* __restrict__ q,
    const IDX* __restrict__ perm, const int* __restrict__ segp,
    float* __restrict__ out, int n)
{
  int wave = threadIdx.x >> 6, lane = threadIdx.x & 63;
  int c = blockIdx.x * 4 + wave;
  if (c >= n) return;
  int p0 = segp[c], p1 = segp[c + 1];

  float a0 = 0.f, a1 = 0.f, a2 = 0.f, a3 = 0.f;
  float d0 = 0.f, d1 = 0.f, d2 = 0.f, d3 = 0.f;
  int p = p0;
  for (; p + 8 <= p1; p += 8) {
    int r0 = __builtin_amdgcn_readfirstlane((int)perm[p]);
    int r1 = __builtin_amdgcn_readfirstlane((int)perm[p + 1]);
    int r2 = __builtin_amdgcn_readfirstlane((int)perm[p + 2]);
    int r3 = __builtin_amdgcn_readfirstlane((int)perm[p + 3]);
    int r4 = __builtin_amdgcn_readfirstlane((int)perm[p + 4]);
    int r5 = __builtin_amdgcn_readfirstlane((int)perm[p + 5]);
    int r6 = __builtin_amdgcn_readfirstlane((int)perm[p + 6]);
    int r7 = __builtin_amdgcn_readfirstlane((int)perm[p + 7]);
    float q0 = q[r0], q1 = q[r1], q2 = q[r2], q3 = q[r3];
    float q4 = q[r4], q5 = q[r5], q6 = q[r6], q7 = q[r7];
    float w0 = bf16dec(Wh[(size_t)r0 * OUT_CH + lane]);
    float w1 = bf16dec(Wh[(size_t)r1 * OUT_CH + lane]);
    float w2 = bf16dec(Wh[(size_t)r2 * OUT_CH + lane]);
    float w3 = bf16dec(Wh[(size_t)r3 * OUT_CH + lane]);
    float w4 = bf16dec(Wh[(size_t)r4 * OUT_CH + lane]);
    float w5 = bf16dec(Wh[(size_t)r5 * OUT_CH + lane]);
    float w6 = bf16dec(Wh[(size_t)r6 * OUT_CH + lane]);
    float w7 = bf16dec(Wh[(size_t)r7 * OUT_CH + lane]);
    a0 = fmaf(q0, w0, a0); d0 += q0;
    a1 = fmaf(q1, w1, a1); d1 += q1;
    a2 = fmaf(q2, w2, a2); d2 += q2;
    a3 = fmaf(q3, w3, a3); d3 += q3;
    a0 = fmaf(q4, w4, a0); d0 += q4;
    a1 = fmaf(q5, w5, a1); d1 += q5;
    a2 = fmaf(q6, w6, a2); d2 += q6;
    a3 = fmaf(q7, w7, a3); d3 += q7;
  }
  for (; p < p1; ++p) {
    int r = __builtin_amdgcn_readfirstlane((int)perm[p]);
    float qq = q[r];
    a0 = fmaf(qq, bf16dec(Wh[(size_t)r * OUT_CH + lane]), a0); d0 += qq;
  }
  float acc = (a0 + a1) + (a2 + a3);
  float den = (d0 + d1) + (d2 + d3);
  float rden = (p1 > p0) ? 1.0f / den : 0.0f;  // empty segment -> elu(0)=0
  acc *= rden;
  out[(size_t)c * OUT_CH + lane] = acc > 0.f ? acc : expm1f(acc);
}

extern "C" void kernel_launch(void* const* d_in, const int* in_sizes, int n_in,
                              void* d_out, int out_size, void* d_ws, size_t ws_size,
                              hipStream_t stream)
{
  const float* x     = (const float*)d_in[0];
  const void*  eidx  = d_in[1];
  const float* W     = (const float*)d_in[2];
  const float* a_src = (const float*)d_in[3];
  const float* a_dst = (const float*)d_in[4];
  float* out = (float*)d_out;

  const int n = in_sizes[0] / IN_CH;   // 50000
  const int E = in_sizes[1] / 2;       // 800000
  const int nb = (n + SCHUNK - 1) / SCHUNK;
  const int ntiles = (n + 15) / 16;

  char* ws = (char*)d_ws;
  size_t off = 0;
  auto alloc = [&](size_t bytes) -> void* {
    void* p = ws + off;
    off = (off + bytes + 255) & ~(size_t)255;
    return p;
  };
  ushort*   Wh     = (ushort*)alloc((size_t)n * OUT_CH * 2);   // bf16
  float*    e      = (float*)alloc((size_t)n * 4);
  float*    q      = (float*)alloc((size_t)n * 4);
  void*     perm   = alloc((size_t)E * 4);   // ushort or uint, by n
  void*     rcbuf  = alloc((size_t)E * 8);   // packed u32 or uint2, by n
  void*     rank   = alloc((size_t)E * 4);   // u16 or u32, by n
  int*      cnt    = (int*)alloc((size_t)n * 4);
  int*      segp   = (int*)alloc((size_t)(n + 1) * 4);
  int*      bsum   = (int*)alloc((size_t)nb * 4);
  ushort*   Whi    = (ushort*)alloc((size_t)IN_CH * OUT_CH * 2);
  unsigned* flag   = (unsigned*)alloc(4);

  int prep_blocks = (n + 255) / 256;
  if (prep_blocks < 65) prep_blocks = 65;
  gat_prep<<<prep_blocks, 256, 0, stream>>>(
      W, Whi, (const unsigned*)eidx, flag, cnt, e, n, 8192);

  // fused phase2: 320 gemm + 448 pass1 persistent blocks = 3 blocks/CU
  const int gemm_blocks = 320;
  const int total_blocks = 768;
  if (n <= 65536) {
    gat_phase2<ushort><<<total_blocks, 256, 0, stream>>>(
        x, Whi, a_src, a_dst, Wh, e, n, ntiles, gemm_blocks,
        eidx, flag, cnt, rcbuf, (ushort*)rank, E);
  } else {
    gat_phase2<unsigned><<<total_blocks, 256, 0, stream>>>(
        x, Whi, a_src, a_dst, Wh, e, n, ntiles, gemm_blocks,
        eidx, flag, cnt, rcbuf, (unsigned*)rank, E);
  }

  scan_partial<<<nb, 256, 0, stream>>>(cnt, bsum, n);
  scan_final<<<nb, 256, 0, stream>>>(cnt, bsum, segp, e, q, n, nb, E);
  if (n <= 65536) {
    gat_scatter<ushort><<<(E + 255) / 256, 256, 0, stream>>>(
        rcbuf, (const ushort*)rank, segp, (ushort*)perm, E);
    gat_aggregate<ushort><<<(n + 3) / 4, 256, 0, stream>>>(
        Wh, q, (const ushort*)perm, segp, out, n);
  } else {
    gat_scatter<unsigned><<<(E + 255) / 256, 256, 0, stream>>>(
        rcbuf, (const unsigned*)rank, segp, (unsigned*)perm, E);
    gat_aggregate<unsigned><<<(n + 3) / 4, 256, 0, stream>>>(
        Wh, q, (const unsigned*)perm, segp, out, n);
  }
}

// Round 30
// 108.934 us; speedup vs baseline: 1.0436x; 1.0436x over previous
//
#include <hip/hip_runtime.h>
#include <math.h>

#define IN_CH 256
#define OUT_CH 64
#define SCHUNK 512  // scan elements per block (needs n <= 256*SCHUNK = 131072)

typedef unsigned short ushort;
typedef unsigned int uint32x4 __attribute__((ext_vector_type(4)));
typedef __bf16 bf16x8 __attribute__((ext_vector_type(8)));
typedef float f32x4 __attribute__((ext_vector_type(4)));

__device__ __forceinline__ ushort bf16rne(float v) {
  unsigned u = __float_as_uint(v);
  return (ushort)((u + 0x7FFFu + ((u >> 16) & 1u)) >> 16);
}
__device__ __forceinline__ float bf16dec(ushort h) {
  return __uint_as_float((unsigned)h << 16);
}
__device__ __forceinline__ unsigned rne16(unsigned u) {   // fp32 bits -> bf16 bits (RNE)
  return (u + 0x7FFFu + ((u >> 16) & 1u)) >> 16;
}

// async global->LDS DMA, 16B per lane: lds dest = base + lane*16 (wave-uniform base),
// global src is PER-LANE. Queued on vmcnt; __syncthreads() drains it.
__device__ __forceinline__ void gload_lds16(const void* g, void* l) {
  __builtin_amdgcn_global_load_lds(
      (const __attribute__((address_space(1))) unsigned int*)g,
      (__attribute__((address_space(3))) unsigned int*)l,
      16, 0, 0);
}

// ---------- K0: fused prep — cnt/e clear + int64 detect + W -> bf16 (RNE) ----------
__global__ __launch_bounds__(256) void gat_prep(
    const float* __restrict__ W, ushort* __restrict__ Whi,
    const unsigned* __restrict__ eidx, unsigned* __restrict__ flag,
    int* __restrict__ cnt, float* __restrict__ e, int n, int npairs)
{
  __shared__ unsigned wsh[4];
  const int b = blockIdx.x, tid = threadIdx.x;
  const int i = b * 256 + tid;
  if (i < n) { cnt[i] = 0; e[i] = 0.f; }
  if (b == 0) {
    unsigned v = 0;
    for (int k = tid; k < npairs; k += 256) v |= eidx[2 * k + 1];
#pragma unroll
    for (int m = 1; m < 64; m <<= 1) v |= __shfl_xor(v, m);
    if ((tid & 63) == 0) wsh[tid >> 6] = v;
    __syncthreads();
    if (tid == 0) *flag = wsh[0] | wsh[1] | wsh[2] | wsh[3];
  } else if (b <= 64) {
    int j = (b - 1) * 256 + tid;                   // 0..16383
    int ee = j & 7, ln = (j >> 3) & 63, ctks = j >> 9;
    int ct = ctks & 3, ks = ctks >> 2;
    int k = ks * 32 + (ln >> 4) * 8 + ee;
    int col = ct * 16 + (ln & 15);
    Whi[j] = bf16rne(W[(size_t)k * OUT_CH + col]);
  }
}

// ---------- K1: fused phase2 — gemm blocks (0..gb-1) CO-RESIDENT with pass1 blocks ----------
// gemm path: DMA-dbuf SINGLE-bf16 MFMA (light). pass1: 2-way unrolled edge pass.
// (256,4), grid 1024 = 512 gemm / 512 pass1 — both paths at max block count.
template <typename IDX>
__global__ __launch_bounds__(256, 4) void gat_phase2(
    const float* __restrict__ x, const ushort* __restrict__ Whi,
    const float* __restrict__ a_src, const float* __restrict__ a_dst,
    ushort* __restrict__ Wh, float* __restrict__ e, int n, int ntiles, int gemm_blocks,
    const void* __restrict__ eidx, const unsigned* __restrict__ flag,
    int* __restrict__ cnt, void* __restrict__ rcbuf, IDX* __restrict__ rank, int E)
{
  __shared__ __align__(16) float Ax[2][16 * 256];  // 2 x 16KB x-frag buffers (gemm path)
  const int tid = threadIdx.x;

  if ((int)blockIdx.x >= gemm_blocks) {
    // ---- pass1 path: persistent, grid-stride, 2 independent chains in flight ----
    const int pb = blockIdx.x - gemm_blocks;
    const int nthr = (gridDim.x - gemm_blocks) * 256;
    const bool is64 = (*flag == 0);
    const long long* p64 = (const long long*)eidx;
    const int* p32 = (const int*)eidx;
    int j = pb * 256 + tid;
    for (; j + nthr < E; j += 2 * nthr) {
      int jA = j, jB = j + nthr;
      int rA, cA, rB, cB;
      if (is64) {
        rA = (int)p64[jA]; cA = (int)p64[(size_t)E + jA];
        rB = (int)p64[jB]; cB = (int)p64[(size_t)E + jB];
      } else {
        rA = p32[jA]; cA = p32[(size_t)E + jA];
        rB = p32[jB]; cB = p32[(size_t)E + jB];
      }
      int kA = atomicAdd(cnt + cA, 1);
      int kB = atomicAdd(cnt + cB, 1);
      if constexpr (sizeof(IDX) == 2) {
        ((unsigned*)rcbuf)[jA] = ((unsigned)cA << 16) | (unsigned)rA;
        ((unsigned*)rcbuf)[jB] = ((unsigned)cB << 16) | (unsigned)rB;
      } else {
        ((uint2*)rcbuf)[jA] = make_uint2((unsigned)rA, (unsigned)cA);
        ((uint2*)rcbuf)[jB] = make_uint2((unsigned)rB, (unsigned)cB);
      }
      rank[jA] = (IDX)kA;
      rank[jB] = (IDX)kB;
    }
    for (; j < E; j += nthr) {
      int r, c;
      if (is64) { r = (int)p64[j]; c = (int)p64[(size_t)E + j]; }
      else      { r = p32[j];      c = p32[(size_t)E + j]; }
      int rk = atomicAdd(cnt + c, 1);
      if constexpr (sizeof(IDX) == 2) {
        ((unsigned*)rcbuf)[j] = ((unsigned)c << 16) | (unsigned)r;
      } else {
        ((uint2*)rcbuf)[j] = make_uint2((unsigned)r, (unsigned)c);
      }
      rank[j] = (IDX)rk;
    }
    return;
  }

  // ---- gemm path ----
  const int lane = tid & 63;
  const int ct = tid >> 6;             // wave id = column tile
  const int lg = lane >> 4;            // k-pack group
  const int li = lane & 15;            // row (A) / col (B/D)
  const int stride = gemm_blocks;

  const int col = ct * 16 + li;
  const float asd = a_src[col] + a_dst[col];

  // issue tile t's 16 DMA chunks into Ax[buf]; wave ct owns chunks ct*4..ct*4+3
  auto issue = [&](int t, int buf) {
    int arow = t * 16 + li; if (arow > n - 1) arow = n - 1;
    const float* __restrict__ xr = x + (size_t)arow * IN_CH;
#pragma unroll
    for (int cc = 0; cc < 4; ++cc) {
      const int chunk = ct * 4 + cc;               // = ks*2 + h
      const int ks = chunk >> 1, h = chunk & 1;
      gload_lds16(xr + ks * 32 + lg * 8 + h * 4, &Ax[buf][chunk * 256]);
    }
  };

  int t = blockIdx.x;
  if (t < ntiles) issue(t, 0);
  __syncthreads();                                 // buf0 DMA drained
  int buf = 0;

  while (t < ntiles) {
    const int tn = t + stride;
    if (tn < ntiles) issue(tn, buf ^ 1);           // async prefetch, can't be sunk

    const int row0 = t * 16;
    f32x4 acc = {0.f, 0.f, 0.f, 0.f};
#pragma unroll
    for (int ks = 0; ks < 8; ++ks) {
      float4 v0 = *(const float4*)&Ax[buf][(ks * 2 + 0) * 256 + lane * 4];
      float4 v1 = *(const float4*)&Ax[buf][(ks * 2 + 1) * 256 + lane * 4];
      unsigned b0 = __float_as_uint(v0.x), b1 = __float_as_uint(v0.y);
      unsigned b2 = __float_as_uint(v0.z), b3 = __float_as_uint(v0.w);
      unsigned b4 = __float_as_uint(v1.x), b5 = __float_as_uint(v1.y);
      unsigned b6 = __float_as_uint(v1.z), b7 = __float_as_uint(v1.w);
      uint32x4 hv = { (rne16(b1) << 16) | rne16(b0),
                      (rne16(b3) << 16) | rne16(b2),
                      (rne16(b5) << 16) | rne16(b4),
                      (rne16(b7) << 16) | rne16(b6) };
      bf16x8 ah = __builtin_bit_cast(bf16x8, hv);
      bf16x8 wh = __builtin_bit_cast(bf16x8, ((const uint4*)Whi)[(ks * 4 + ct) * 64 + lane]);
      acc = __builtin_amdgcn_mfma_f32_16x16x32_bf16(ah, wh, acc, 0, 0, 0);
    }

    // epilogue: Wh bf16 store + e partial via atomicAdd
#pragma unroll
    for (int r = 0; r < 4; ++r) {
      int row = row0 + lg * 4 + r;
      bool ok = row < n;
      if (ok) Wh[(size_t)row * OUT_CH + col] = bf16rne(acc[r]);
      float pe = acc[r] * asd;
      pe += __shfl_xor(pe, 1); pe += __shfl_xor(pe, 2);
      pe += __shfl_xor(pe, 4); pe += __shfl_xor(pe, 8);
      if (ok && li == 0) atomicAdd(e + row, pe);   // 4 ct-partials per row
    }

    __syncthreads();     // drains t+1's DMAs; buf safe to overwrite next iter
    buf ^= 1;
    t = tn;
  }
}

// ---------- K4a/b: hierarchical exclusive scan of cnt -> segp; q = exp(e) fused ----------
__global__ __launch_bounds__(256) void scan_partial(
    const int* __restrict__ cnt, int* __restrict__ bsum, int n)
{
  int base = blockIdx.x * SCHUNK;
  int tid = threadIdx.x;
  int s = 0;
  int i0 = base + tid, i1 = base + tid + 256;
  if (i0 < n) s += cnt[i0];
  if (i1 < n) s += cnt[i1];
#pragma unroll
  for (int m = 1; m < 64; m <<= 1) s += __shfl_xor(s, m);
  __shared__ int ws[4];
  if ((tid & 63) == 0) ws[tid >> 6] = s;
  __syncthreads();
  if (tid == 0) bsum[blockIdx.x] = ws[0] + ws[1] + ws[2] + ws[3];
}

__global__ __launch_bounds__(256) void scan_final(
    const int* __restrict__ cnt, const int* __restrict__ bsum,
    int* __restrict__ segp, const float* __restrict__ e, float* __restrict__ q,
    int n, int nb, int E)
{
  __shared__ int sh[256];
  __shared__ int bexcl_sh;
  int tid = threadIdx.x;
  int bv = (tid < nb) ? bsum[tid] : 0;
  sh[tid] = bv;
  __syncthreads();
  for (int off = 1; off < 256; off <<= 1) {
    int add = (tid >= off) ? sh[tid - off] : 0;
    __syncthreads();
    sh[tid] += add;
    __syncthreads();
  }
  if (tid == 0) bexcl_sh = sh[blockIdx.x] - bsum[blockIdx.x];
  __syncthreads();
  int bexcl = bexcl_sh;
  __syncthreads();   // done reading sh as bsum-scan; reuse below

  int base = blockIdx.x * SCHUNK;
  int i0 = base + 2 * tid, i1 = i0 + 1;
  int c0 = (i0 < n) ? cnt[i0] : 0;
  int c1 = (i1 < n) ? cnt[i1] : 0;
  int ps = c0 + c1;
  sh[tid] = ps;
  __syncthreads();
  for (int off = 1; off < 256; off <<= 1) {
    int add = (tid >= off) ? sh[tid - off] : 0;
    __syncthreads();
    sh[tid] += add;
    __syncthreads();
  }
  int excl = sh[tid] - ps + bexcl;
  if (i0 < n) { segp[i0] = excl;      q[i0] = __expf(fminf(e[i0], 80.f)); }
  if (i1 < n) { segp[i1] = excl + c0; q[i1] = __expf(fminf(e[i1], 80.f)); }
  if (blockIdx.x == 0 && tid == 0) segp[n] = E;
}

// ---------- K5: atomic-free CSR scatter: perm[segp[c]+rank] = r ----------
template <typename IDX>
__global__ void gat_scatter(
    const void* __restrict__ rcbuf, const IDX* __restrict__ rank,
    const int* __restrict__ segp, IDX* __restrict__ perm, int E)
{
  int j = blockIdx.x * blockDim.x + threadIdx.x;
  if (j >= E) return;
  unsigned r, c;
  if constexpr (sizeof(IDX) == 2) {
    unsigned p = ((const unsigned*)rcbuf)[j];
    r = p & 0xFFFFu; c = p >> 16;
  } else {
    uint2 p = ((const uint2*)rcbuf)[j];
    r = p.x; c = p.y;
  }
  perm[segp[c] + (int)rank[j]] = (IDX)r;
}

// ---------- K6: aggregate + ELU; factorized softmax, scalarized gathers ----------
// out_c = sum_r q[r]*Wh[r] / sum_r q[r]  — the q[c] factor cancels analytically.
template <typename IDX>
__global__ __launch_bounds__(256) void gat_aggregate(
    const ushort* __restrict__ Wh, const float* __restrict__ q,
    const IDX* __restrict__ perm, const int* __restrict__ segp,
    float* __restrict__ out, int n)
{
  int wave = threadIdx.x >> 6, lane = threadIdx.x & 63;
  int c = blockIdx.x * 4 + wave;
  if (c >= n) return;
  int p0 = segp[c], p1 = segp[c + 1];

  float a0 = 0.f, a1 = 0.f, a2 = 0.f, a3 = 0.f;
  float d0 = 0.f, d1 = 0.f, d2 = 0.f, d3 = 0.f;
  int p = p0;
  for (; p + 8 <= p1; p += 8) {
    int r0 = __builtin_amdgcn_readfirstlane((int)perm[p]);
    int r1 = __builtin_amdgcn_readfirstlane((int)perm[p + 1]);
    int r2 = __builtin_amdgcn_readfirstlane((int)perm[p + 2]);
    int r3 = __builtin_amdgcn_readfirstlane((int)perm[p + 3]);
    int r4 = __builtin_amdgcn_readfirstlane((int)perm[p + 4]);
    int r5 = __builtin_amdgcn_readfirstlane((int)perm[p + 5]);
    int r6 = __builtin_amdgcn_readfirstlane((int)perm[p + 6]);
    int r7 = __builtin_amdgcn_readfirstlane((int)perm[p + 7]);
    float q0 = q[r0], q1 = q[r1], q2 = q[r2], q3 = q[r3];
    float q4 = q[r4], q5 = q[r5], q6 = q[r6], q7 = q[r7];
    float w0 = bf16dec(Wh[(size_t)r0 * OUT_CH + lane]);
    float w1 = bf16dec(Wh[(size_t)r1 * OUT_CH + lane]);
    float w2 = bf16dec(Wh[(size_t)r2 * OUT_CH + lane]);
    float w3 = bf16dec(Wh[(size_t)r3 * OUT_CH + lane]);
    float w4 = bf16dec(Wh[(size_t)r4 * OUT_CH + lane]);
    float w5 = bf16dec(Wh[(size_t)r5 * OUT_CH + lane]);
    float w6 = bf16dec(Wh[(size_t)r6 * OUT_CH + lane]);
    float w7 = bf16dec(Wh[(size_t)r7 * OUT_CH + lane]);
    a0 = fmaf(q0, w0, a0); d0 += q0;
    a1 = fmaf(q1, w1, a1); d1 += q1;
    a2 = fmaf(q2, w2, a2); d2 += q2;
    a3 = fmaf(q3, w3, a3); d3 += q3;
    a0 = fmaf(q4, w4, a0); d0 += q4;
    a1 = fmaf(q5, w5, a1); d1 += q5;
    a2 = fmaf(q6, w6, a2); d2 += q6;
    a3 = fmaf(q7, w7, a3); d3 += q7;
  }
  for (; p < p1; ++p) {
    int r = __builtin_amdgcn_readfirstlane((int)perm[p]);
    float qq = q[r];
    a0 = fmaf(qq, bf16dec(Wh[(size_t)r * OUT_CH + lane]), a0); d0 += qq;
  }
  float acc = (a0 + a1) + (a2 + a3);
  float den = (d0 + d1) + (d2 + d3);
  float rden = (p1 > p0) ? 1.0f / den : 0.0f;  // empty segment -> elu(0)=0
  acc *= rden;
  out[(size_t)c * OUT_CH + lane] = acc > 0.f ? acc : expm1f(acc);
}

extern "C" void kernel_launch(void* const* d_in, const int* in_sizes, int n_in,
                              void* d_out, int out_size, void* d_ws, size_t ws_size,
                              hipStream_t stream)
{
  const float* x     = (const float*)d_in[0];
  const void*  eidx  = d_in[1];
  const float* W     = (const float*)d_in[2];
  const float* a_src = (const float*)d_in[3];
  const float* a_dst = (const float*)d_in[4];
  float* out = (float*)d_out;

  const int n = in_sizes[0] / IN_CH;   // 50000
  const int E = in_sizes[1] / 2;       // 800000
  const int nb = (n + SCHUNK - 1) / SCHUNK;
  const int ntiles = (n + 15) / 16;

  char* ws = (char*)d_ws;
  size_t off = 0;
  auto alloc = [&](size_t bytes) -> void* {
    void* p = ws + off;
    off = (off + bytes + 255) & ~(size_t)255;
    return p;
  };
  ushort*   Wh     = (ushort*)alloc((size_t)n * OUT_CH * 2);   // bf16
  float*    e      = (float*)alloc((size_t)n * 4);
  float*    q      = (float*)alloc((size_t)n * 4);
  void*     perm   = alloc((size_t)E * 4);   // ushort or uint, by n
  void*     rcbuf  = alloc((size_t)E * 8);   // packed u32 or uint2, by n
  void*     rank   = alloc((size_t)E * 4);   // u16 or u32, by n
  int*      cnt    = (int*)alloc((size_t)n * 4);
  int*      segp   = (int*)alloc((size_t)(n + 1) * 4);
  int*      bsum   = (int*)alloc((size_t)nb * 4);
  ushort*   Whi    = (ushort*)alloc((size_t)IN_CH * OUT_CH * 2);
  unsigned* flag   = (unsigned*)alloc(4);

  int prep_blocks = (n + 255) / 256;
  if (prep_blocks < 65) prep_blocks = 65;
  gat_prep<<<prep_blocks, 256, 0, stream>>>(
      W, Whi, (const unsigned*)eidx, flag, cnt, e, n, 8192);

  // fused phase2: 512 gemm + 512 pass1 persistent blocks = 4 blocks/CU
  const int gemm_blocks = 512;
  const int total_blocks = 1024;
  if (n <= 65536) {
    gat_phase2<ushort><<<total_blocks, 256, 0, stream>>>(
        x, Whi, a_src, a_dst, Wh, e, n, ntiles, gemm_blocks,
        eidx, flag, cnt, rcbuf, (ushort*)rank, E);
  } else {
    gat_phase2<unsigned><<<total_blocks, 256, 0, stream>>>(
        x, Whi, a_src, a_dst, Wh, e, n, ntiles, gemm_blocks,
        eidx, flag, cnt, rcbuf, (unsigned*)rank, E);
  }

  scan_partial<<<nb, 256, 0, stream>>>(cnt, bsum, n);
  scan_final<<<nb, 256, 0, stream>>>(cnt, bsum, segp, e, q, n, nb, E);
  if (n <= 65536) {
    gat_scatter<ushort><<<(E + 255) / 256, 256, 0, stream>>>(
        rcbuf, (const ushort*)rank, segp, (ushort*)perm, E);
    gat_aggregate<ushort><<<(n + 3) / 4, 256, 0, stream>>>(
        Wh, q, (const ushort*)perm, segp, out, n);
  } else {
    gat_scatter<unsigned><<<(E + 255) / 256, 256, 0, stream>>>(
        rcbuf, (const unsigned*)rank, segp, (unsigned*)perm, E);
    gat_aggregate<unsigned><<<(n + 3) / 4, 256, 0, stream>>>(
        Wh, q, (const unsigned*)perm, segp, out, n);
  }
}

// Round 31
// 102.650 us; speedup vs baseline: 1.1075x; 1.0612x over previous
//
#include <hip/hip_runtime.h>
#include <math.h>

#define IN_CH 256
#define OUT_CH 64
#define SCHUNK 512  // scan elements per block (needs n <= 256*SCHUNK = 131072)

typedef unsigned short ushort;
typedef unsigned int uint32x4 __attribute__((ext_vector_type(4)));
typedef __bf16 bf16x8 __attribute__((ext_vector_type(8)));
typedef float f32x4 __attribute__((ext_vector_type(4)));

__device__ __forceinline__ ushort bf16rne(float v) {
  unsigned u = __float_as_uint(v);
  return (ushort)((u + 0x7FFFu + ((u >> 16) & 1u)) >> 16);
}
__device__ __forceinline__ float bf16dec(ushort h) {
  return __uint_as_float((unsigned)h << 16);
}

// async global->LDS DMA, 16B per lane: lds dest = base + lane*16 (wave-uniform base),
// global src is PER-LANE. Queued on vmcnt; __syncthreads() drains it.
__device__ __forceinline__ void gload_lds16(const void* g, void* l) {
  __builtin_amdgcn_global_load_lds(
      (const __attribute__((address_space(1))) unsigned int*)g,
      (__attribute__((address_space(3))) unsigned int*)l,
      16, 0, 0);
}

// ---------- K0: fused prep — cnt/e clear + int64 detect + W split ----------
__global__ __launch_bounds__(256) void gat_prep(
    const float* __restrict__ W, ushort* __restrict__ Whi, ushort* __restrict__ Wlo,
    const unsigned* __restrict__ eidx, unsigned* __restrict__ flag,
    int* __restrict__ cnt, float* __restrict__ e, int n, int npairs)
{
  __shared__ unsigned wsh[4];
  const int b = blockIdx.x, tid = threadIdx.x;
  const int i = b * 256 + tid;
  if (i < n) { cnt[i] = 0; e[i] = 0.f; }
  if (b == 0) {
    unsigned v = 0;
    for (int k = tid; k < npairs; k += 256) v |= eidx[2 * k + 1];
#pragma unroll
    for (int m = 1; m < 64; m <<= 1) v |= __shfl_xor(v, m);
    if ((tid & 63) == 0) wsh[tid >> 6] = v;
    __syncthreads();
    if (tid == 0) *flag = wsh[0] | wsh[1] | wsh[2] | wsh[3];
  } else if (b <= 64) {
    int j = (b - 1) * 256 + tid;                   // 0..16383
    int ee = j & 7, ln = (j >> 3) & 63, ctks = j >> 9;
    int ct = ctks & 3, ks = ctks >> 2;
    int k = ks * 32 + (ln >> 4) * 8 + ee;
    int col = ct * 16 + (ln & 15);
    float v = W[(size_t)k * OUT_CH + col];
    unsigned u = __float_as_uint(v);
    unsigned hb = u & 0xFFFF0000u;                 // truncation split (lo absorbs error)
    Whi[j] = (ushort)(hb >> 16);
    Wlo[j] = bf16rne(v - __uint_as_float(hb));
  }
}

// ---------- K1: fused phase2 — gemm blocks (0..gb-1) CO-RESIDENT with pass1 blocks ----------
// R27 configuration (measured best): gemm = DMA-dbuf split-bf16 MFMA, W from L2,
// 32KB LDS, (256,3). Split 448 gemm / 320 pass1. Simple (non-unrolled) pass1.
template <typename IDX>
__global__ __launch_bounds__(256, 3) void gat_phase2(
    const float* __restrict__ x, const ushort* __restrict__ Whi, const ushort* __restrict__ Wlo,
    const float* __restrict__ a_src, const float* __restrict__ a_dst,
    ushort* __restrict__ Wh, float* __restrict__ e, int n, int ntiles, int gemm_blocks,
    const void* __restrict__ eidx, const unsigned* __restrict__ flag,
    int* __restrict__ cnt, void* __restrict__ rcbuf, IDX* __restrict__ rank, int E)
{
  __shared__ __align__(16) float Ax[2][16 * 256];  // 2 x 16KB x-frag buffers (gemm path)
  const int tid = threadIdx.x;

  if ((int)blockIdx.x >= gemm_blocks) {
    // ---- pass1 path: persistent, grid-stride over edges ----
    const int pb = blockIdx.x - gemm_blocks;
    const int nthr = (gridDim.x - gemm_blocks) * 256;
    const bool is64 = (*flag == 0);
    for (int j = pb * 256 + tid; j < E; j += nthr) {
      int r, c;
      if (is64) {
        const long long* p = (const long long*)eidx;
        r = (int)p[j]; c = (int)p[(size_t)E + j];
      } else {
        const int* p = (const int*)eidx;
        r = p[j]; c = p[(size_t)E + j];
      }
      int rk = atomicAdd(cnt + c, 1);
      if constexpr (sizeof(IDX) == 2) {
        ((unsigned*)rcbuf)[j] = ((unsigned)c << 16) | (unsigned)r;
      } else {
        ((uint2*)rcbuf)[j] = make_uint2((unsigned)r, (unsigned)c);
      }
      rank[j] = (IDX)rk;
    }
    return;
  }

  // ---- gemm path ----
  const int lane = tid & 63;
  const int ct = tid >> 6;             // wave id = column tile
  const int lg = lane >> 4;            // k-pack group
  const int li = lane & 15;            // row (A) / col (B/D)
  const int stride = gemm_blocks;

  const int col = ct * 16 + li;
  const float asd = a_src[col] + a_dst[col];

  // issue tile t's 16 DMA chunks into Ax[buf]; wave ct owns chunks ct*4..ct*4+3
  auto issue = [&](int t, int buf) {
    int arow = t * 16 + li; if (arow > n - 1) arow = n - 1;
    const float* __restrict__ xr = x + (size_t)arow * IN_CH;
#pragma unroll
    for (int cc = 0; cc < 4; ++cc) {
      const int chunk = ct * 4 + cc;               // = ks*2 + h
      const int ks = chunk >> 1, h = chunk & 1;
      gload_lds16(xr + ks * 32 + lg * 8 + h * 4, &Ax[buf][chunk * 256]);
    }
  };

  int t = blockIdx.x;
  if (t < ntiles) issue(t, 0);
  __syncthreads();                                 // buf0 DMA drained
  int buf = 0;

  while (t < ntiles) {
    const int tn = t + stride;
    if (tn < ntiles) issue(tn, buf ^ 1);           // async prefetch, can't be sunk

    const int row0 = t * 16;
    f32x4 acc = {0.f, 0.f, 0.f, 0.f};
#pragma unroll
    for (int ks = 0; ks < 8; ++ks) {
      float4 v0 = *(const float4*)&Ax[buf][(ks * 2 + 0) * 256 + lane * 4];
      float4 v1 = *(const float4*)&Ax[buf][(ks * 2 + 1) * 256 + lane * 4];
      unsigned b0 = __float_as_uint(v0.x), b1 = __float_as_uint(v0.y);
      unsigned b2 = __float_as_uint(v0.z), b3 = __float_as_uint(v0.w);
      unsigned b4 = __float_as_uint(v1.x), b5 = __float_as_uint(v1.y);
      unsigned b6 = __float_as_uint(v1.z), b7 = __float_as_uint(v1.w);
      uint32x4 hv = { (b1 & 0xFFFF0000u) | (b0 >> 16),
                      (b3 & 0xFFFF0000u) | (b2 >> 16),
                      (b5 & 0xFFFF0000u) | (b4 >> 16),
                      (b7 & 0xFFFF0000u) | (b6 >> 16) };
      bf16x8 ah = __builtin_bit_cast(bf16x8, hv);
      float l0 = v0.x - __uint_as_float(b0 & 0xFFFF0000u);
      float l1 = v0.y - __uint_as_float(b1 & 0xFFFF0000u);
      float l2 = v0.z - __uint_as_float(b2 & 0xFFFF0000u);
      float l3 = v0.w - __uint_as_float(b3 & 0xFFFF0000u);
      float l4 = v1.x - __uint_as_float(b4 & 0xFFFF0000u);
      float l5 = v1.y - __uint_as_float(b5 & 0xFFFF0000u);
      float l6 = v1.z - __uint_as_float(b6 & 0xFFFF0000u);
      float l7 = v1.w - __uint_as_float(b7 & 0xFFFF0000u);
      bf16x8 al = { (__bf16)l0, (__bf16)l1, (__bf16)l2, (__bf16)l3,
                    (__bf16)l4, (__bf16)l5, (__bf16)l6, (__bf16)l7 };
      bf16x8 wh = __builtin_bit_cast(bf16x8, ((const uint4*)Whi)[(ks * 4 + ct) * 64 + lane]);
      bf16x8 wl = __builtin_bit_cast(bf16x8, ((const uint4*)Wlo)[(ks * 4 + ct) * 64 + lane]);
      acc = __builtin_amdgcn_mfma_f32_16x16x32_bf16(ah, wh, acc, 0, 0, 0);
      acc = __builtin_amdgcn_mfma_f32_16x16x32_bf16(al, wh, acc, 0, 0, 0);
      acc = __builtin_amdgcn_mfma_f32_16x16x32_bf16(ah, wl, acc, 0, 0, 0);
      acc = __builtin_amdgcn_mfma_f32_16x16x32_bf16(al, wl, acc, 0, 0, 0);
    }

    // epilogue: Wh bf16 store + e partial via atomicAdd
#pragma unroll
    for (int r = 0; r < 4; ++r) {
      int row = row0 + lg * 4 + r;
      bool ok = row < n;
      if (ok) Wh[(size_t)row * OUT_CH + col] = bf16rne(acc[r]);
      float pe = acc[r] * asd;
      pe += __shfl_xor(pe, 1); pe += __shfl_xor(pe, 2);
      pe += __shfl_xor(pe, 4); pe += __shfl_xor(pe, 8);
      if (ok && li == 0) atomicAdd(e + row, pe);   // 4 ct-partials per row
    }

    __syncthreads();     // drains t+1's DMAs; buf safe to overwrite next iter
    buf ^= 1;
    t = tn;
  }
}

// ---------- K4a/b: hierarchical exclusive scan of cnt -> segp; q = exp(e) fused ----------
__global__ __launch_bounds__(256) void scan_partial(
    const int* __restrict__ cnt, int* __restrict__ bsum, int n)
{
  int base = blockIdx.x * SCHUNK;
  int tid = threadIdx.x;
  int s = 0;
  int i0 = base + tid, i1 = base + tid + 256;
  if (i0 < n) s += cnt[i0];
  if (i1 < n) s += cnt[i1];
#pragma unroll
  for (int m = 1; m < 64; m <<= 1) s += __shfl_xor(s, m);
  __shared__ int ws[4];
  if ((tid & 63) == 0) ws[tid >> 6] = s;
  __syncthreads();
  if (tid == 0) bsum[blockIdx.x] = ws[0] + ws[1] + ws[2] + ws[3];
}

__global__ __launch_bounds__(256) void scan_final(
    const int* __restrict__ cnt, const int* __restrict__ bsum,
    int* __restrict__ segp, const float* __restrict__ e, float* __restrict__ q,
    int n, int nb, int E)
{
  __shared__ int sh[256];
  __shared__ int bexcl_sh;
  int tid = threadIdx.x;
  int bv = (tid < nb) ? bsum[tid] : 0;
  sh[tid] = bv;
  __syncthreads();
  for (int off = 1; off < 256; off <<= 1) {
    int add = (tid >= off) ? sh[tid - off] : 0;
    __syncthreads();
    sh[tid] += add;
    __syncthreads();
  }
  if (tid == 0) bexcl_sh = sh[blockIdx.x] - bsum[blockIdx.x];
  __syncthreads();
  int bexcl = bexcl_sh;
  __syncthreads();   // done reading sh as bsum-scan; reuse below

  int base = blockIdx.x * SCHUNK;
  int i0 = base + 2 * tid, i1 = i0 + 1;
  int c0 = (i0 < n) ? cnt[i0] : 0;
  int c1 = (i1 < n) ? cnt[i1] : 0;
  int ps = c0 + c1;
  sh[tid] = ps;
  __syncthreads();
  for (int off = 1; off < 256; off <<= 1) {
    int add = (tid >= off) ? sh[tid - off] : 0;
    __syncthreads();
    sh[tid] += add;
    __syncthreads();
  }
  int excl = sh[tid] - ps + bexcl;
  if (i0 < n) { segp[i0] = excl;      q[i0] = __expf(fminf(e[i0], 80.f)); }
  if (i1 < n) { segp[i1] = excl + c0; q[i1] = __expf(fminf(e[i1], 80.f)); }
  if (blockIdx.x == 0 && tid == 0) segp[n] = E;
}

// ---------- K5: atomic-free CSR scatter: perm[segp[c]+rank] = r ----------
template <typename IDX>
__global__ void gat_scatter(
    const void* __restrict__ rcbuf, const IDX* __restrict__ rank,
    const int* __restrict__ segp, IDX* __restrict__ perm, int E)
{
  int j = blockIdx.x * blockDim.x + threadIdx.x;
  if (j >= E) return;
  unsigned r, c;
  if constexpr (sizeof(IDX) == 2) {
    unsigned p = ((const unsigned*)rcbuf)[j];
    r = p & 0xFFFFu; c = p >> 16;
  } else {
    uint2 p = ((const uint2*)rcbuf)[j];
    r = p.x; c = p.y;
  }
  perm[segp[c] + (int)rank[j]] = (IDX)r;
}

// ---------- K6: aggregate + ELU; factorized softmax, scalarized gathers ----------
// out_c = sum_r q[r]*Wh[r] / sum_r q[r]  — the q[c] factor cancels analytically.
template <typename IDX>
__global__ __launch_bounds__(256) void gat_aggregate(
    const ushort* __restrict__ Wh, const float* __restrict__ q,
    const IDX* __restrict__ perm, const int* __restrict__ segp,
    float* __restrict__ out, int n)
{
  int wave = threadIdx.x >> 6, lane = threadIdx.x & 63;
  int c = blockIdx.x * 4 + wave;
  if (c >= n) return;
  int p0 = segp[c], p1 = segp[c + 1];

  float a0 = 0.f, a1 = 0.f, a2 = 0.f, a3 = 0.f;
  float d0 = 0.f, d1 = 0.f, d2 = 0.f, d3 = 0.f;
  int p = p0;
  for (; p + 8 <= p1; p += 8) {
    int r0 = __builtin_amdgcn_readfirstlane((int)perm[p]);
    int r1 = __builtin_amdgcn_readfirstlane((int)perm[p + 1]);
    int r2 = __builtin_amdgcn_readfirstlane((int)perm[p + 2]);
    int r3 = __builtin_amdgcn_readfirstlane((int)perm[p + 3]);
    int r4 = __builtin_amdgcn_readfirstlane((int)perm[p + 4]);
    int r5 = __builtin_amdgcn_readfirstlane((int)perm[p + 5]);
    int r6 = __builtin_amdgcn_readfirstlane((int)perm[p + 6]);
    int r7 = __builtin_amdgcn_readfirstlane((int)perm[p + 7]);
    float q0 = q[r0], q1 = q[r1], q2 = q[r2], q3 = q[r3];
    float q4 = q[r4], q5 = q[r5], q6 = q[r6], q7 = q[r7];
    float w0 = bf16dec(Wh[(size_t)r0 * OUT_CH + lane]);
    float w1 = bf16dec(Wh[(size_t)r1 * OUT_CH + lane]);
    float w2 = bf16dec(Wh[(size_t)r2 * OUT_CH + lane]);
    float w3 = bf16dec(Wh[(size_t)r3 * OUT_CH + lane]);
    float w4 = bf16dec(Wh[(size_t)r4 * OUT_CH + lane]);
    float w5 = bf16dec(Wh[(size_t)r5 * OUT_CH + lane]);
    float w6 = bf16dec(Wh[(size_t)r6 * OUT_CH + lane]);
    float w7 = bf16dec(Wh[(size_t)r7 * OUT_CH + lane]);
    a0 = fmaf(q0, w0, a0); d0 += q0;
    a1 = fmaf(q1, w1, a1); d1 += q1;
    a2 = fmaf(q2, w2, a2); d2 += q2;
    a3 = fmaf(q3, w3, a3); d3 += q3;
    a0 = fmaf(q4, w4, a0); d0 += q4;
    a1 = fmaf(q5, w5, a1); d1 += q5;
    a2 = fmaf(q6, w6, a2); d2 += q6;
    a3 = fmaf(q7, w7, a3); d3 += q7;
  }
  for (; p < p1; ++p) {
    int r = __builtin_amdgcn_readfirstlane((int)perm[p]);
    float qq = q[r];
    a0 = fmaf(qq, bf16dec(Wh[(size_t)r * OUT_CH + lane]), a0); d0 += qq;
  }
  float acc = (a0 + a1) + (a2 + a3);
  float den = (d0 + d1) + (d2 + d3);
  float rden = (p1 > p0) ? 1.0f / den : 0.0f;  // empty segment -> elu(0)=0
  acc *= rden;
  out[(size_t)c * OUT_CH + lane] = acc > 0.f ? acc : expm1f(acc);
}

extern "C" void kernel_launch(void* const* d_in, const int* in_sizes, int n_in,
                              void* d_out, int out_size, void* d_ws, size_t ws_size,
                              hipStream_t stream)
{
  const float* x     = (const float*)d_in[0];
  const void*  eidx  = d_in[1];
  const float* W     = (const float*)d_in[2];
  const float* a_src = (const float*)d_in[3];
  const float* a_dst = (const float*)d_in[4];
  float* out = (float*)d_out;

  const int n = in_sizes[0] / IN_CH;   // 50000
  const int E = in_sizes[1] / 2;       // 800000
  const int nb = (n + SCHUNK - 1) / SCHUNK;
  const int ntiles = (n + 15) / 16;

  char* ws = (char*)d_ws;
  size_t off = 0;
  auto alloc = [&](size_t bytes) -> void* {
    void* p = ws + off;
    off = (off + bytes + 255) & ~(size_t)255;
    return p;
  };
  ushort*   Wh     = (ushort*)alloc((size_t)n * OUT_CH * 2);   // bf16
  float*    e      = (float*)alloc((size_t)n * 4);
  float*    q      = (float*)alloc((size_t)n * 4);
  void*     perm   = alloc((size_t)E * 4);   // ushort or uint, by n
  void*     rcbuf  = alloc((size_t)E * 8);   // packed u32 or uint2, by n
  void*     rank   = alloc((size_t)E * 4);   // u16 or u32, by n
  int*      cnt    = (int*)alloc((size_t)n * 4);
  int*      segp   = (int*)alloc((size_t)(n + 1) * 4);
  int*      bsum   = (int*)alloc((size_t)nb * 4);
  ushort*   Whi    = (ushort*)alloc((size_t)IN_CH * OUT_CH * 2);
  ushort*   Wlo    = (ushort*)alloc((size_t)IN_CH * OUT_CH * 2);
  unsigned* flag   = (unsigned*)alloc(4);

  int prep_blocks = (n + 255) / 256;
  if (prep_blocks < 65) prep_blocks = 65;
  gat_prep<<<prep_blocks, 256, 0, stream>>>(
      W, Whi, Wlo, (const unsigned*)eidx, flag, cnt, e, n, 8192);

  // fused phase2: 448 gemm + 320 pass1 persistent blocks = 3 blocks/CU
  const int gemm_blocks = 448;
  const int total_blocks = 768;
  if (n <= 65536) {
    gat_phase2<ushort><<<total_blocks, 256, 0, stream>>>(
        x, Whi, Wlo, a_src, a_dst, Wh, e, n, ntiles, gemm_blocks,
        eidx, flag, cnt, rcbuf, (ushort*)rank, E);
  } else {
    gat_phase2<unsigned><<<total_blocks, 256, 0, stream>>>(
        x, Whi, Wlo, a_src, a_dst, Wh, e, n, ntiles, gemm_blocks,
        eidx, flag, cnt, rcbuf, (unsigned*)rank, E);
  }

  scan_partial<<<nb, 256, 0, stream>>>(cnt, bsum, n);
  scan_final<<<nb, 256, 0, stream>>>(cnt, bsum, segp, e, q, n, nb, E);
  if (n <= 65536) {
    gat_scatter<ushort><<<(E + 255) / 256, 256, 0, stream>>>(
        rcbuf, (const ushort*)rank, segp, (ushort*)perm, E);
    gat_aggregate<ushort><<<(n + 3) / 4, 256, 0, stream>>>(
        Wh, q, (const ushort*)perm, segp, out, n);
  } else {
    gat_scatter<unsigned><<<(E + 255) / 256, 256, 0, stream>>>(
        rcbuf, (const unsigned*)rank, segp, (unsigned*)perm, E);
    gat_aggregate<unsigned><<<(n + 3) / 4, 256, 0, stream>>>(
        Wh, q, (const unsigned*)perm, segp, out, n);
  }
}